// Round 1
// baseline (45.852 us; speedup 1.0000x reference)
//
#include <hip/hip_runtime.h>

// Problem: shape (32, 2, 640, 640) fp32 pred/target.
// out = sum_central(d^2)/3276800 + sum_periph(|d|)/9830400, d = pred - target,
// central = columns [240,400) of the last dim, sums over batch+both channels.
//
// Memory-bound streaming reduction: 209.7 MB read -> ~33 us floor at 6.3 TB/s.
// Two-pass deterministic reduction (no atomics): partials in d_ws.

#define NBLOCKS 2048
#define NTHREADS 256

__global__ __launch_bounds__(NTHREADS) void
partial_kernel(const float* __restrict__ pred,
               const float* __restrict__ targ,
               float2* __restrict__ partials,
               long n4) {
    const float4* __restrict__ p4 = (const float4*)pred;
    const float4* __restrict__ t4 = (const float4*)targ;

    long tid = (long)blockIdx.x * blockDim.x + threadIdx.x;
    long stride = (long)gridDim.x * blockDim.x;

    float acc_sq = 0.0f;
    float acc_abs = 0.0f;

    for (long i = tid; i < n4; i += stride) {
        float4 p = p4[i];
        float4 t = t4[i];
        float d0 = p.x - t.x;
        float d1 = p.y - t.y;
        float d2 = p.z - t.z;
        float d3 = p.w - t.w;
        // Row is 160 float4s wide; central float4 range is [60, 100).
        // Band boundaries (240, 400) are 4-aligned, so a float4 never straddles.
        int w4 = (int)(i % 160);
        if (w4 >= 60 && w4 < 100) {
            acc_sq += d0 * d0 + d1 * d1 + d2 * d2 + d3 * d3;
        } else {
            acc_abs += fabsf(d0) + fabsf(d1) + fabsf(d2) + fabsf(d3);
        }
    }

    // Wave (64-lane) shuffle reduction.
    for (int off = 32; off > 0; off >>= 1) {
        acc_sq  += __shfl_down(acc_sq,  off, 64);
        acc_abs += __shfl_down(acc_abs, off, 64);
    }

    __shared__ float s_sq[NTHREADS / 64];
    __shared__ float s_abs[NTHREADS / 64];
    int lane = threadIdx.x & 63;
    int wave = threadIdx.x >> 6;
    if (lane == 0) {
        s_sq[wave] = acc_sq;
        s_abs[wave] = acc_abs;
    }
    __syncthreads();
    if (threadIdx.x == 0) {
        float sq = 0.0f, ab = 0.0f;
        #pragma unroll
        for (int w = 0; w < NTHREADS / 64; ++w) {
            sq += s_sq[w];
            ab += s_abs[w];
        }
        partials[blockIdx.x] = make_float2(sq, ab);
    }
}

__global__ __launch_bounds__(64) void
final_kernel(const float2* __restrict__ partials,
             float* __restrict__ out,
             int nparts) {
    double acc_sq = 0.0;
    double acc_abs = 0.0;
    for (int i = threadIdx.x; i < nparts; i += 64) {
        float2 v = partials[i];
        acc_sq += (double)v.x;
        acc_abs += (double)v.y;
    }
    for (int off = 32; off > 0; off >>= 1) {
        acc_sq  += __shfl_down(acc_sq,  off, 64);
        acc_abs += __shfl_down(acc_abs, off, 64);
    }
    if (threadIdx.x == 0) {
        // Per-channel means summed over 2 channels:
        // central denom = 32*640*160 = 3276800, periphery = 32*640*480 = 9830400
        out[0] = (float)(acc_sq / 3276800.0 + acc_abs / 9830400.0);
    }
}

extern "C" void kernel_launch(void* const* d_in, const int* in_sizes, int n_in,
                              void* d_out, int out_size, void* d_ws, size_t ws_size,
                              hipStream_t stream) {
    const float* pred = (const float*)d_in[0];
    const float* targ = (const float*)d_in[1];
    float* out = (float*)d_out;
    float2* partials = (float2*)d_ws;

    long n = (long)in_sizes[0];       // 26,214,400 elements
    long n4 = n / 4;                  // 6,553,600 float4 per tensor... (see below)
    // NOTE: in_sizes[0] is the flat element count of pred = 32*2*640*640.
    // n4 = 13,107,200 float4 loads per tensor.

    partial_kernel<<<NBLOCKS, NTHREADS, 0, stream>>>(pred, targ, partials, n4);
    final_kernel<<<1, 64, 0, stream>>>(partials, out, NBLOCKS);
}

// Round 2
// 42.141 us; speedup vs baseline: 1.0881x; 1.0881x over previous
//
#include <hip/hip_runtime.h>

// Problem: shape (32, 2, 640, 640) fp32 pred/target.
// out = sum_central(d^2)/3276800 + sum_periph(|d|)/9830400, d = pred - target,
// central = columns [240,400) of last dim, sums over batch+both channels.
//
// Memory-bound: 209.7 MB read (~half served by 256MB L3 on replay).
// R1 structure: exact work partition, compile-time trip count, per-thread
// constant central/periphery predicate (stride is a multiple of 160 float4s).
//
// Geometry: N4 = 26214400/4 = 6,553,600 float4 per tensor.
//   NBLOCKS=1280 x 256 threads = 327,680 threads = 5 blocks/CU (even).
//   ITERS = 6,553,600 / 327,680 = 20 (compile-time).
//   stride 327,680 = 160*2048  ->  (tid + k*stride) % 160 == tid % 160.

#define NBLOCKS 1280
#define NTHREADS 256
#define NTHREADS_TOTAL (NBLOCKS * NTHREADS)   // 327680
#define ITERS 20

__global__ __launch_bounds__(NTHREADS) void
partial_kernel(const float4* __restrict__ p4,
               const float4* __restrict__ t4,
               float2* __restrict__ partials) {
    int tid = blockIdx.x * NTHREADS + threadIdx.x;

    // Row is 160 float4s; central float4 columns are [60, 100).
    // Constant per thread because the grid stride is a multiple of 160.
    int w4 = tid % 160;
    bool central = (w4 >= 60) && (w4 < 100);

    float acc_sq = 0.0f;
    float acc_abs = 0.0f;

    #pragma unroll 4
    for (int k = 0; k < ITERS; ++k) {
        int i = tid + k * NTHREADS_TOTAL;
        float4 p = p4[i];
        float4 t = t4[i];
        float d0 = p.x - t.x;
        float d1 = p.y - t.y;
        float d2 = p.z - t.z;
        float d3 = p.w - t.w;
        float s = d0 * d0 + d1 * d1 + d2 * d2 + d3 * d3;
        float a = fabsf(d0) + fabsf(d1) + fabsf(d2) + fabsf(d3);
        acc_sq  += central ? s : 0.0f;
        acc_abs += central ? 0.0f : a;
    }

    // Wave (64-lane) shuffle reduction.
    for (int off = 32; off > 0; off >>= 1) {
        acc_sq  += __shfl_down(acc_sq,  off, 64);
        acc_abs += __shfl_down(acc_abs, off, 64);
    }

    __shared__ float s_sq[NTHREADS / 64];
    __shared__ float s_abs[NTHREADS / 64];
    int lane = threadIdx.x & 63;
    int wave = threadIdx.x >> 6;
    if (lane == 0) {
        s_sq[wave] = acc_sq;
        s_abs[wave] = acc_abs;
    }
    __syncthreads();
    if (threadIdx.x == 0) {
        float sq = 0.0f, ab = 0.0f;
        #pragma unroll
        for (int w = 0; w < NTHREADS / 64; ++w) {
            sq += s_sq[w];
            ab += s_abs[w];
        }
        partials[blockIdx.x] = make_float2(sq, ab);
    }
}

__global__ __launch_bounds__(64) void
final_kernel(const float2* __restrict__ partials,
             float* __restrict__ out,
             int nparts) {
    double acc_sq = 0.0;
    double acc_abs = 0.0;
    for (int i = threadIdx.x; i < nparts; i += 64) {
        float2 v = partials[i];
        acc_sq += (double)v.x;
        acc_abs += (double)v.y;
    }
    for (int off = 32; off > 0; off >>= 1) {
        acc_sq  += __shfl_down(acc_sq,  off, 64);
        acc_abs += __shfl_down(acc_abs, off, 64);
    }
    if (threadIdx.x == 0) {
        // central denom = 32*640*160 = 3276800, periphery = 32*640*480 = 9830400
        out[0] = (float)(acc_sq / 3276800.0 + acc_abs / 9830400.0);
    }
}

extern "C" void kernel_launch(void* const* d_in, const int* in_sizes, int n_in,
                              void* d_out, int out_size, void* d_ws, size_t ws_size,
                              hipStream_t stream) {
    const float4* pred = (const float4*)d_in[0];
    const float4* targ = (const float4*)d_in[1];
    float* out = (float*)d_out;
    float2* partials = (float2*)d_ws;

    partial_kernel<<<NBLOCKS, NTHREADS, 0, stream>>>(pred, targ, partials);
    final_kernel<<<1, 64, 0, stream>>>(partials, out, NBLOCKS);
}